// Round 6
// baseline (1716.487 us; speedup 1.0000x reference)
//
#include <hip/hip_runtime.h>
#include <math.h>

#define NTOT 16384
#define NSEG 2048
#define CH_STRIDE 8320ull   // 128 chunk rows * 65 floats per task

// ws float offsets
#define OFF_HH   0ull         // 16384*256 (hc reuses after layer-1 consumers done)
#define OFF_XC   4194304ull   // 16384*256
#define OFF_S1H  8388608ull   // 65536
#define OFF_S2H  8454144ull   // 65536
#define OFF_S1O  8519680ull   // 16384
#define OFF_S2O  8536064ull   // 16384
#define OFF_WN   8552448ull   // 32*2048
#define OFF_SIDX 8617984ull   // 32*2048 ints
#define OFF_TH   8683520ull   // 32*2048
#define OFF_QIDX 8749056ull   // 32*2048 ints
#define OFF_KQ   8814592ull   // 32*2048 ints
#define OFF_M2   8880128ull   // 32
#define OFF_CHA  8880160ull   // 32*8320
#define OFF_CHS  9146400ull   // 32*8320 -> end 9412640 floats (37.7 MB)

__device__ inline unsigned long long pack_key(float v, int idx) {
    unsigned u = __float_as_uint(v);
    u = (u & 0x80000000u) ? ~u : (u | 0x80000000u);
    return ((unsigned long long)u << 32) | (unsigned)idx;
}
__device__ inline float unpack_key(unsigned long long k) {
    unsigned u = (unsigned)(k >> 32);
    u = (u & 0x80000000u) ? (u ^ 0x80000000u) : ~u;
    return __uint_as_float(u);
}
__device__ inline unsigned long long shfl_xor_u64(unsigned long long x, int mask) {
    unsigned lo = (unsigned)x, hi = (unsigned)(x >> 32);
    lo = (unsigned)__shfl_xor((int)lo, mask, 64);
    hi = (unsigned)__shfl_xor((int)hi, mask, 64);
    return ((unsigned long long)hi << 32) | lo;
}

// verified hybrid register/shuffle/LDS bitonic sort of 2048 u64 (2 elems/thread, 1024 thr)
__device__ inline void bitonic2048(unsigned long long& a0, unsigned long long& a1,
                                   unsigned long long* sA, unsigned long long* sB, int tid) {
    for (int k = 2; k <= 2048; k <<= 1) {
        const bool up0 = (tid & k) == 0;
        const bool up1 = (((tid + 1024) & k) == 0);
        for (int j = k >> 1; j > 0; j >>= 1) {
            if (j >= 1024) {
                unsigned long long lo = a0 < a1 ? a0 : a1;
                unsigned long long hi = a0 < a1 ? a1 : a0;
                a0 = up0 ? lo : hi;
                a1 = up0 ? hi : lo;
            } else if (j >= 64) {
                __syncthreads();
                sA[tid] = a0; sB[tid] = a1;
                __syncthreads();
                unsigned long long p0 = sA[tid ^ j], p1 = sB[tid ^ j];
                bool lower = (tid & j) == 0;
                a0 = ((a0 < p0) == (lower == up0)) ? a0 : p0;
                a1 = ((a1 < p1) == (lower == up1)) ? a1 : p1;
            } else {
                unsigned long long p0 = shfl_xor_u64(a0, j);
                unsigned long long p1 = shfl_xor_u64(a1, j);
                bool lower = (tid & j) == 0;
                a0 = ((a0 < p0) == (lower == up0)) ? a0 : p0;
                a1 = ((a1 < p1) == (lower == up1)) ? a1 : p1;
            }
        }
    }
}

// ---------------- GEMM 1 + fused s1/s2 projection (verified) ----------------
__global__ __launch_bounds__(256) void gemm1_k(const float* __restrict__ X,
                                               const float* __restrict__ Wh,
                                               const float* __restrict__ aH,
                                               float* __restrict__ hh,
                                               float* __restrict__ s1h,
                                               float* __restrict__ s2h) {
    __shared__ float As[64][68];
    __shared__ float Bs[64][68];
    const int tid = threadIdx.x;
    const int bm = blockIdx.x, h = blockIdx.y;
    const int c0 = tid & 63, r0 = tid >> 6;
#pragma unroll
    for (int r = 0; r < 16; ++r) {
        int row = r0 + r * 4;
        As[c0][row] = X[(size_t)(bm * 64 + row) * 64 + c0];
        Bs[row][c0] = Wh[h * 4096 + row * 64 + c0];
    }
    __syncthreads();
    const int tx = tid & 15, ty = tid >> 4;
    const int m0 = ty * 4, n0 = tx * 4;
    float acc[4][4] = {};
#pragma unroll
    for (int kk = 0; kk < 64; ++kk) {
        float4 a = *(const float4*)&As[kk][m0];
        float4 b = *(const float4*)&Bs[kk][n0];
        acc[0][0] += a.x * b.x; acc[0][1] += a.x * b.y; acc[0][2] += a.x * b.z; acc[0][3] += a.x * b.w;
        acc[1][0] += a.y * b.x; acc[1][1] += a.y * b.y; acc[1][2] += a.y * b.z; acc[1][3] += a.y * b.w;
        acc[2][0] += a.z * b.x; acc[2][1] += a.z * b.y; acc[2][2] += a.z * b.z; acc[2][3] += a.z * b.w;
        acc[3][0] += a.w * b.x; acc[3][1] += a.w * b.y; acc[3][2] += a.w * b.z; acc[3][3] += a.w * b.w;
    }
#pragma unroll
    for (int i = 0; i < 4; ++i) {
        float4 v = make_float4(acc[i][0], acc[i][1], acc[i][2], acc[i][3]);
        *(float4*)&hh[(size_t)(bm * 64 + m0 + i) * 256 + h * 64 + n0] = v;
    }
#pragma unroll
    for (int i = 0; i < 4; ++i) {
        float p1 = 0.f, p2 = 0.f;
#pragma unroll
        for (int jj = 0; jj < 4; ++jj) {
            p1 += acc[i][jj] * aH[h * 128 + n0 + jj];
            p2 += acc[i][jj] * aH[h * 128 + 64 + n0 + jj];
        }
#pragma unroll
        for (int off = 8; off; off >>= 1) {
            p1 += __shfl_xor(p1, off, 16);
            p2 += __shfl_xor(p2, off, 16);
        }
        if (tx == 0) {
            s1h[h * NTOT + bm * 64 + m0 + i] = p1;
            s2h[h * NTOT + bm * 64 + m0 + i] = p2;
        }
    }
}

// ---------------- GEMM 2 + fused s1/s2 projection (verified) ----------------
__global__ __launch_bounds__(256) void gemm2_k(const float* __restrict__ XC,
                                               const float* __restrict__ Wo,
                                               const float* __restrict__ aO,
                                               float* __restrict__ hc,
                                               float* __restrict__ s1o,
                                               float* __restrict__ s2o) {
    __shared__ float As[64][68];
    __shared__ float Bs[64][68];
    const int tid = threadIdx.x;
    const int bm = blockIdx.x;
    const int c0 = tid & 63, r0 = tid >> 6;
    const int tx = tid & 15, ty = tid >> 4;
    const int m0 = ty * 4, n0 = tx * 4;
    float acc[4][4] = {};
    for (int kt = 0; kt < 4; ++kt) {
#pragma unroll
        for (int r = 0; r < 16; ++r) {
            int row = r0 + r * 4;
            As[c0][row] = XC[(size_t)(bm * 64 + row) * 256 + kt * 64 + c0];
            Bs[row][c0] = Wo[(kt * 64 + row) * 64 + c0];
        }
        __syncthreads();
#pragma unroll
        for (int kk = 0; kk < 64; ++kk) {
            float4 a = *(const float4*)&As[kk][m0];
            float4 b = *(const float4*)&Bs[kk][n0];
            acc[0][0] += a.x * b.x; acc[0][1] += a.x * b.y; acc[0][2] += a.x * b.z; acc[0][3] += a.x * b.w;
            acc[1][0] += a.y * b.x; acc[1][1] += a.y * b.y; acc[1][2] += a.y * b.z; acc[1][3] += a.y * b.w;
            acc[2][0] += a.z * b.x; acc[2][1] += a.z * b.y; acc[2][2] += a.z * b.z; acc[2][3] += a.z * b.w;
            acc[3][0] += a.w * b.x; acc[3][1] += a.w * b.y; acc[3][2] += a.w * b.z; acc[3][3] += a.w * b.w;
        }
        __syncthreads();
    }
#pragma unroll
    for (int i = 0; i < 4; ++i) {
        float4 v = make_float4(acc[i][0], acc[i][1], acc[i][2], acc[i][3]);
        *(float4*)&hc[(size_t)(bm * 64 + m0 + i) * 64 + n0] = v;
    }
#pragma unroll
    for (int i = 0; i < 4; ++i) {
        float p1 = 0.f, p2 = 0.f;
#pragma unroll
        for (int jj = 0; jj < 4; ++jj) {
            p1 += acc[i][jj] * aO[n0 + jj];
            p2 += acc[i][jj] * aO[64 + n0 + jj];
        }
#pragma unroll
        for (int off = 8; off; off >>= 1) {
            p1 += __shfl_xor(p1, off, 16);
            p2 += __shfl_xor(p2, off, 16);
        }
        if (tx == 0) {
            s1o[bm * 64 + m0 + i] = p1;
            s2o[bm * 64 + m0 + i] = p2;
        }
    }
}

// ---- sortprep: sort keys (s2), sort queries (-s1), compute per-query split k ----
__global__ __launch_bounds__(1024) void sortprep_k(const float* __restrict__ s2_all,
                                                   const float* __restrict__ s1_all,
                                                   int heads,
                                                   float* __restrict__ g_wN, int* __restrict__ g_sidx,
                                                   float* __restrict__ g_M2,
                                                   float* __restrict__ g_th, int* __restrict__ g_qidx,
                                                   int* __restrict__ g_kq) {
    __shared__ unsigned long long sA[1024];
    __shared__ unsigned long long sB[1024];
    __shared__ float sval[NSEG];
    const int tid = threadIdx.x, t = blockIdx.x;
    const int g = t / heads, h = t % heads;
    const float* s2p = s2_all + (size_t)h * NTOT + (size_t)g * NSEG;
    const float* s1p = s1_all + (size_t)h * NTOT + (size_t)g * NSEG;
    const size_t o = (size_t)t * NSEG;
    // pass 1: sort keys ascending
    unsigned long long a0 = pack_key(s2p[tid], tid);
    unsigned long long a1 = pack_key(s2p[tid + 1024], tid + 1024);
    bitonic2048(a0, a1, sA, sB, tid);
    float v0 = unpack_key(a0), v1 = unpack_key(a1);
    sval[tid] = v0; sval[tid + 1024] = v1;
    __syncthreads();
    const float M2 = sval[NSEG - 1];
    g_sidx[o + tid] = (int)(unsigned)(a0 & 0xffffffffu);
    g_sidx[o + tid + 1024] = (int)(unsigned)(a1 & 0xffffffffu);
    g_wN[o + tid] = __expf(0.2f * (v0 - M2));
    g_wN[o + tid + 1024] = __expf(0.2f * (v1 - M2));
    if (tid == 0) g_M2[t] = M2;
    // pass 2: sort queries by threshold th = -s1 ascending
    unsigned long long b0 = pack_key(-s1p[tid], tid);
    unsigned long long b1 = pack_key(-s1p[tid + 1024], tid + 1024);
    bitonic2048(b0, b1, sA, sB, tid);
    float th0 = unpack_key(b0), th1 = unpack_key(b1);
    // per-query split: k = #{keys <= th}  (verified search loop)
    int lo = 0, hi = NSEG;
    while (lo < hi) { int mid = (lo + hi) >> 1; if (sval[mid] <= th0) lo = mid + 1; else hi = mid; }
    int k0 = lo;
    lo = 0; hi = NSEG;
    while (lo < hi) { int mid = (lo + hi) >> 1; if (sval[mid] <= th1) lo = mid + 1; else hi = mid; }
    int k1 = lo;
    g_th[o + tid] = th0;            g_th[o + tid + 1024] = th1;
    g_qidx[o + tid] = (int)(unsigned)(b0 & 0xffffffffu);
    g_qidx[o + tid + 1024] = (int)(unsigned)(b1 & 0xffffffffu);
    g_kq[o + tid] = k0;             g_kq[o + tid + 1024] = k1;
}

// ---- raw chunk sums: one wave per 16-element chunk, machine-wide (verified pattern) ----
__global__ __launch_bounds__(256) void chunks_k(const float* __restrict__ V,
                                                int heads, int vstride,
                                                const int* __restrict__ g_sidx,
                                                const float* __restrict__ g_wN,
                                                float* __restrict__ g_chA, float* __restrict__ g_chS) {
    const int t = blockIdx.y, g = t / heads, h = t % heads;
    const int wv = threadIdx.x >> 6, lane = threadIdx.x & 63;
    const int c = blockIdx.x * 4 + wv, base = c * 16;
    const float* Vp = V + (size_t)g * NSEG * vstride + h * 64;
    float wn_l = 0.f; int si_l = 0;
    if (lane < 16) {
        wn_l = g_wN[(size_t)t * NSEG + base + lane];
        si_l = g_sidx[(size_t)t * NSEG + base + lane];
    }
    float sa = 0.f, swa = 0.f, ss = 0.f, sws = 0.f;
#pragma unroll
    for (int j = 0; j < 16; ++j) {
        float wn = __shfl(wn_l, j, 64);
        int row = __shfl(si_l, j, 64);
        float v = Vp[(size_t)row * vstride + lane];
        float w2 = wn * wn, wp = w2 * w2 * wn;
        sa += wn * v; swa += wn;
        ss += wp * v; sws += wp;
    }
    size_t oo = (size_t)t * CH_STRIDE + (size_t)c * 65;
    g_chA[oo + lane] = sa;
    g_chS[oo + lane] = ss;
    if (lane == 0) { g_chA[oo + 64] = swa; g_chS[oo + 64] = sws; }
}

__device__ inline int lb_kq(const int* kq, int val) {
    int lo = 0, hi = NSEG;
    while (lo < hi) { int mid = (lo + hi) >> 1; if (kq[mid] < val) lo = mid + 1; else hi = mid; }
    return lo;
}

// ---- fused scan+walk+serve: wave per chunk; serves all queries with k in [16c,16c+16) ----
template <int MODE>  // 0: ELU -> xc ; 1: ELU + log_softmax -> out
__global__ __launch_bounds__(256) void tabquery_k(const float* __restrict__ V,
                                                  int heads, int vstride, int ostride,
                                                  const int* __restrict__ g_sidx,
                                                  const float* __restrict__ g_wN,
                                                  const float* __restrict__ g_chA,
                                                  const float* __restrict__ g_chS,
                                                  const float* __restrict__ g_M2,
                                                  const float* __restrict__ g_th,
                                                  const int* __restrict__ g_qidx,
                                                  const int* __restrict__ g_kq,
                                                  float* __restrict__ out) {
    __shared__ float chA[8320];
    __shared__ float chS[8320];
    const int tid = threadIdx.x;
    const int t = blockIdx.y, g = t / heads, h = t % heads;
    const int wv = tid >> 6, lane = tid & 63;
    const int c = blockIdx.x * 4 + wv, base = c * 16;
    // cooperative LDS load of this task's raw chunk sums
    const float4* gA4 = (const float4*)(g_chA + (size_t)t * CH_STRIDE);
    const float4* gS4 = (const float4*)(g_chS + (size_t)t * CH_STRIDE);
    for (int i = tid; i < 2080; i += 256) {
        ((float4*)chA)[i] = gA4[i];
        ((float4*)chS)[i] = gS4[i];
    }
    // prefetch walk data while LDS fills
    const float* Vp = V + (size_t)g * NSEG * vstride + h * 64;
    const int* sidx = g_sidx + (size_t)t * NSEG + base;
    const float* wnp = g_wN + (size_t)t * NSEG + base;
    float wn[16], vv[16];
#pragma unroll
    for (int j = 0; j < 16; ++j) wn[j] = wnp[j];
#pragma unroll
    for (int j = 0; j < 16; ++j) vv[j] = Vp[(size_t)sidx[j] * vstride + lane];
    const float M2 = g_M2[t];
    const int* kq = g_kq + (size_t)t * NSEG;
    const float* thp = g_th + (size_t)t * NSEG;
    const int* qip = g_qidx + (size_t)t * NSEG;
    float* outp = out + (size_t)g * NSEG * ostride + h * 64;
    int idx = lb_kq(kq, base);
    int hiq = (c == 127) ? NSEG : lb_kq(kq, base + 16);
    __syncthreads();
    // register scans over chunk rows (LDS)
    float accA = 0.f, scaA = 0.f;
    for (int cp = 0; cp < c; ++cp) { accA += chA[cp * 65 + lane]; scaA += chA[cp * 65 + 64]; }
    float accS = 0.f, scaS = 0.f;
    for (int cp = c; cp < 128; ++cp) { accS += chS[cp * 65 + lane]; scaS += chS[cp * 65 + 64]; }
    // walk the chunk, serving queries in-stream
    for (int j = 0; j <= 16; ++j) {
        int kcur = base + j;
        if (j == 16 && c != 127) break;
        while (idx < hiq && kq[idx] == kcur) {
            float thv = thp[idx];
            int q = qip[idx];
            float s1q = -thv;
            float cc = __expf(-0.8f * fmaxf(s1q + M2, 0.f));
            float o = (accS + cc * accA) / (scaS + cc * scaA);
            o = o > 0.f ? o : expm1f(o);  // ELU
            if (MODE == 0) {
                outp[(size_t)q * ostride + lane] = o;
            } else {
                float m = o;
#pragma unroll
                for (int off = 32; off; off >>= 1) m = fmaxf(m, __shfl_xor(m, off, 64));
                float e = __expf(o - m);
#pragma unroll
                for (int off = 32; off; off >>= 1) e += __shfl_xor(e, off, 64);
                outp[(size_t)q * ostride + lane] = o - m - __logf(e);
            }
            ++idx;
        }
        if (j < 16) {
            float w = wn[j], w2 = w * w, wp = w2 * w2 * w;
            accA += w * vv[j];  scaA += w;
            accS -= wp * vv[j]; scaS -= wp;
        }
    }
}

extern "C" void kernel_launch(void* const* d_in, const int* in_sizes, int n_in,
                              void* d_out, int out_size, void* d_ws, size_t ws_size,
                              hipStream_t stream) {
    const float* h_states = (const float*)d_in[0];
    const float* W_heads = (const float*)d_in[1];
    const float* a_heads = (const float*)d_in[2];
    const float* W_out = (const float*)d_in[3];
    const float* a_out = (const float*)d_in[4];
    float* w = (float*)d_ws;
    float* hh = w + OFF_HH;
    float* xc = w + OFF_XC;
    float* hc = w + OFF_HH;  // reuse: hh dead after layer-1 tabquery
    float* s1h = w + OFF_S1H;
    float* s2h = w + OFF_S2H;
    float* s1o = w + OFF_S1O;
    float* s2o = w + OFF_S2O;
    float* g_wN = w + OFF_WN;
    int* g_sidx = (int*)(w + OFF_SIDX);
    float* g_th = w + OFF_TH;
    int* g_qidx = (int*)(w + OFF_QIDX);
    int* g_kq = (int*)(w + OFF_KQ);
    float* g_M2 = w + OFF_M2;
    float* g_chA = w + OFF_CHA;
    float* g_chS = w + OFF_CHS;
    float* outp = (float*)d_out;

    gemm1_k<<<dim3(256, 4), 256, 0, stream>>>(h_states, W_heads, a_heads, hh, s1h, s2h);
    sortprep_k<<<32, 1024, 0, stream>>>(s2h, s1h, 4, g_wN, g_sidx, g_M2, g_th, g_qidx, g_kq);
    chunks_k<<<dim3(32, 32), 256, 0, stream>>>(hh, 4, 256, g_sidx, g_wN, g_chA, g_chS);
    tabquery_k<0><<<dim3(32, 32), 256, 0, stream>>>(hh, 4, 256, 256, g_sidx, g_wN, g_chA, g_chS,
                                                    g_M2, g_th, g_qidx, g_kq, xc);
    gemm2_k<<<256, 256, 0, stream>>>(xc, W_out, a_out, hc, s1o, s2o);
    sortprep_k<<<8, 1024, 0, stream>>>(s2o, s1o, 1, g_wN, g_sidx, g_M2, g_th, g_qidx, g_kq);
    chunks_k<<<dim3(32, 8), 256, 0, stream>>>(hc, 1, 64, g_sidx, g_wN, g_chA, g_chS);
    tabquery_k<1><<<dim3(32, 8), 256, 0, stream>>>(hc, 1, 64, 64, g_sidx, g_wN, g_chA, g_chS,
                                                   g_M2, g_th, g_qidx, g_kq, outp);
}

// Round 7
// 375.770 us; speedup vs baseline: 4.5679x; 4.5679x over previous
//
#include <hip/hip_runtime.h>
#include <math.h>

#define NTOT 16384
#define NSEG 2048
#define CROWS 8385ull   // 129 rows * 65 floats per task (scanned chunk tables + boundary row)

// ws float offsets
#define OFF_HH   0ull         // 16384*256 (hc reuses after layer-1 consumers done)
#define OFF_XC   4194304ull   // 16384*256
#define OFF_S1H  8388608ull   // 65536
#define OFF_S2H  8454144ull   // 65536
#define OFF_S1O  8519680ull   // 16384
#define OFF_S2O  8536064ull   // 16384
#define OFF_WN   8552448ull   // 32*2048
#define OFF_TH   8617984ull   // 32*2048
#define OFF_QIDX 8683520ull   // 32*2048 ints
#define OFF_KQ   8749056ull   // 32*2048 ints
#define OFF_M2   8814592ull   // 32
#define OFF_CHA  8814624ull   // 32*8385
#define OFF_CHS  9082944ull   // 32*8385
#define OFF_VS   9351264ull   // 32*2048*64 -> end 13545568 floats (54.2 MB)

__device__ inline unsigned long long pack_key(float v, int idx) {
    unsigned u = __float_as_uint(v);
    u = (u & 0x80000000u) ? ~u : (u | 0x80000000u);
    return ((unsigned long long)u << 32) | (unsigned)idx;
}
__device__ inline float unpack_key(unsigned long long k) {
    unsigned u = (unsigned)(k >> 32);
    u = (u & 0x80000000u) ? (u ^ 0x80000000u) : ~u;
    return __uint_as_float(u);
}
__device__ inline unsigned long long shfl_xor_u64(unsigned long long x, int mask) {
    unsigned lo = (unsigned)x, hi = (unsigned)(x >> 32);
    lo = (unsigned)__shfl_xor((int)lo, mask, 64);
    hi = (unsigned)__shfl_xor((int)hi, mask, 64);
    return ((unsigned long long)hi << 32) | lo;
}

// verified hybrid register/shuffle/LDS bitonic sort of 2048 u64 (2 elems/thread, 1024 thr)
__device__ inline void bitonic2048(unsigned long long& a0, unsigned long long& a1,
                                   unsigned long long* sA, unsigned long long* sB, int tid) {
    for (int k = 2; k <= 2048; k <<= 1) {
        const bool up0 = (tid & k) == 0;
        const bool up1 = (((tid + 1024) & k) == 0);
        for (int j = k >> 1; j > 0; j >>= 1) {
            if (j >= 1024) {
                unsigned long long lo = a0 < a1 ? a0 : a1;
                unsigned long long hi = a0 < a1 ? a1 : a0;
                a0 = up0 ? lo : hi;
                a1 = up0 ? hi : lo;
            } else if (j >= 64) {
                __syncthreads();
                sA[tid] = a0; sB[tid] = a1;
                __syncthreads();
                unsigned long long p0 = sA[tid ^ j], p1 = sB[tid ^ j];
                bool lower = (tid & j) == 0;
                a0 = ((a0 < p0) == (lower == up0)) ? a0 : p0;
                a1 = ((a1 < p1) == (lower == up1)) ? a1 : p1;
            } else {
                unsigned long long p0 = shfl_xor_u64(a0, j);
                unsigned long long p1 = shfl_xor_u64(a1, j);
                bool lower = (tid & j) == 0;
                a0 = ((a0 < p0) == (lower == up0)) ? a0 : p0;
                a1 = ((a1 < p1) == (lower == up1)) ? a1 : p1;
            }
        }
    }
}

// ---------------- GEMM 1 + fused s1/s2 projection (verified) ----------------
__global__ __launch_bounds__(256) void gemm1_k(const float* __restrict__ X,
                                               const float* __restrict__ Wh,
                                               const float* __restrict__ aH,
                                               float* __restrict__ hh,
                                               float* __restrict__ s1h,
                                               float* __restrict__ s2h) {
    __shared__ float As[64][68];
    __shared__ float Bs[64][68];
    const int tid = threadIdx.x;
    const int bm = blockIdx.x, h = blockIdx.y;
    const int c0 = tid & 63, r0 = tid >> 6;
#pragma unroll
    for (int r = 0; r < 16; ++r) {
        int row = r0 + r * 4;
        As[c0][row] = X[(size_t)(bm * 64 + row) * 64 + c0];
        Bs[row][c0] = Wh[h * 4096 + row * 64 + c0];
    }
    __syncthreads();
    const int tx = tid & 15, ty = tid >> 4;
    const int m0 = ty * 4, n0 = tx * 4;
    float acc[4][4] = {};
#pragma unroll
    for (int kk = 0; kk < 64; ++kk) {
        float4 a = *(const float4*)&As[kk][m0];
        float4 b = *(const float4*)&Bs[kk][n0];
        acc[0][0] += a.x * b.x; acc[0][1] += a.x * b.y; acc[0][2] += a.x * b.z; acc[0][3] += a.x * b.w;
        acc[1][0] += a.y * b.x; acc[1][1] += a.y * b.y; acc[1][2] += a.y * b.z; acc[1][3] += a.y * b.w;
        acc[2][0] += a.z * b.x; acc[2][1] += a.z * b.y; acc[2][2] += a.z * b.z; acc[2][3] += a.z * b.w;
        acc[3][0] += a.w * b.x; acc[3][1] += a.w * b.y; acc[3][2] += a.w * b.z; acc[3][3] += a.w * b.w;
    }
#pragma unroll
    for (int i = 0; i < 4; ++i) {
        float4 v = make_float4(acc[i][0], acc[i][1], acc[i][2], acc[i][3]);
        *(float4*)&hh[(size_t)(bm * 64 + m0 + i) * 256 + h * 64 + n0] = v;
    }
#pragma unroll
    for (int i = 0; i < 4; ++i) {
        float p1 = 0.f, p2 = 0.f;
#pragma unroll
        for (int jj = 0; jj < 4; ++jj) {
            p1 += acc[i][jj] * aH[h * 128 + n0 + jj];
            p2 += acc[i][jj] * aH[h * 128 + 64 + n0 + jj];
        }
#pragma unroll
        for (int off = 8; off; off >>= 1) {
            p1 += __shfl_xor(p1, off, 16);
            p2 += __shfl_xor(p2, off, 16);
        }
        if (tx == 0) {
            s1h[h * NTOT + bm * 64 + m0 + i] = p1;
            s2h[h * NTOT + bm * 64 + m0 + i] = p2;
        }
    }
}

// ---------------- GEMM 2 + fused s1/s2 projection (verified) ----------------
__global__ __launch_bounds__(256) void gemm2_k(const float* __restrict__ XC,
                                               const float* __restrict__ Wo,
                                               const float* __restrict__ aO,
                                               float* __restrict__ hc,
                                               float* __restrict__ s1o,
                                               float* __restrict__ s2o) {
    __shared__ float As[64][68];
    __shared__ float Bs[64][68];
    const int tid = threadIdx.x;
    const int bm = blockIdx.x;
    const int c0 = tid & 63, r0 = tid >> 6;
    const int tx = tid & 15, ty = tid >> 4;
    const int m0 = ty * 4, n0 = tx * 4;
    float acc[4][4] = {};
    for (int kt = 0; kt < 4; ++kt) {
#pragma unroll
        for (int r = 0; r < 16; ++r) {
            int row = r0 + r * 4;
            As[c0][row] = XC[(size_t)(bm * 64 + row) * 256 + kt * 64 + c0];
            Bs[row][c0] = Wo[(kt * 64 + row) * 64 + c0];
        }
        __syncthreads();
#pragma unroll
        for (int kk = 0; kk < 64; ++kk) {
            float4 a = *(const float4*)&As[kk][m0];
            float4 b = *(const float4*)&Bs[kk][n0];
            acc[0][0] += a.x * b.x; acc[0][1] += a.x * b.y; acc[0][2] += a.x * b.z; acc[0][3] += a.x * b.w;
            acc[1][0] += a.y * b.x; acc[1][1] += a.y * b.y; acc[1][2] += a.y * b.z; acc[1][3] += a.y * b.w;
            acc[2][0] += a.z * b.x; acc[2][1] += a.z * b.y; acc[2][2] += a.z * b.z; acc[2][3] += a.z * b.w;
            acc[3][0] += a.w * b.x; acc[3][1] += a.w * b.y; acc[3][2] += a.w * b.z; acc[3][3] += a.w * b.w;
        }
        __syncthreads();
    }
#pragma unroll
    for (int i = 0; i < 4; ++i) {
        float4 v = make_float4(acc[i][0], acc[i][1], acc[i][2], acc[i][3]);
        *(float4*)&hc[(size_t)(bm * 64 + m0 + i) * 64 + n0] = v;
    }
#pragma unroll
    for (int i = 0; i < 4; ++i) {
        float p1 = 0.f, p2 = 0.f;
#pragma unroll
        for (int jj = 0; jj < 4; ++jj) {
            p1 += acc[i][jj] * aO[n0 + jj];
            p2 += acc[i][jj] * aO[64 + n0 + jj];
        }
#pragma unroll
        for (int off = 8; off; off >>= 1) {
            p1 += __shfl_xor(p1, off, 16);
            p2 += __shfl_xor(p2, off, 16);
        }
        if (tx == 0) {
            s1o[bm * 64 + m0 + i] = p1;
            s2o[bm * 64 + m0 + i] = p2;
        }
    }
}

// ---- fused: key sort + V reorder + chunk sums + scans + query sort + per-query k ----
__global__ __launch_bounds__(1024) void sortchunkscan_k(const float* __restrict__ s2_all,
                                                        const float* __restrict__ s1_all,
                                                        const float* __restrict__ V,
                                                        int heads, int vstride,
                                                        float* __restrict__ g_wN,
                                                        float* __restrict__ g_M2,
                                                        float* __restrict__ g_th,
                                                        int* __restrict__ g_qidx,
                                                        int* __restrict__ g_kq,
                                                        float* __restrict__ g_chA, float* __restrict__ g_chS,
                                                        float* __restrict__ g_Vs) {
    __shared__ unsigned long long sA[1024];
    __shared__ unsigned long long sB[1024];
    __shared__ float sval[NSEG];
    __shared__ float swn[NSEG];
    __shared__ int ssi[NSEG];
    __shared__ float chA[8320];
    __shared__ float chS[8320];
    __shared__ float btA[4][65];
    __shared__ float btS[4][65];
    __shared__ float sM2;
    const int tid = threadIdx.x, t = blockIdx.x;
    const int g = t / heads, h = t % heads;
    const float* s2p = s2_all + (size_t)h * NTOT + (size_t)g * NSEG;
    const float* s1p = s1_all + (size_t)h * NTOT + (size_t)g * NSEG;
    const float* Vp = V + (size_t)g * NSEG * vstride + h * 64;
    float* Vst = g_Vs + (size_t)t * NSEG * 64;
    const size_t o = (size_t)t * NSEG;

    // ---- phase A: sort keys ascending ----
    unsigned long long a0 = pack_key(s2p[tid], tid);
    unsigned long long a1 = pack_key(s2p[tid + 1024], tid + 1024);
    bitonic2048(a0, a1, sA, sB, tid);
    float v0 = unpack_key(a0), v1 = unpack_key(a1);
    sval[tid] = v0; sval[tid + 1024] = v1;
    if (tid == 1023) sM2 = v1;
    __syncthreads();
    const float M2 = sM2;
    int i0 = (int)(unsigned)(a0 & 0xffffffffu);
    int i1 = (int)(unsigned)(a1 & 0xffffffffu);
    float w0 = __expf(0.2f * (v0 - M2));
    float w1 = __expf(0.2f * (v1 - M2));
    g_wN[o + tid] = w0; g_wN[o + tid + 1024] = w1;
    swn[tid] = w0; swn[tid + 1024] = w1;
    ssi[tid] = i0; ssi[tid + 1024] = i1;
    if (tid == 0) g_M2[t] = M2;
    __syncthreads();
    // ---- phase B: chunk sums + sorted-V write (wave wv: chunks 8wv..8wv+7; lane = dim) ----
    const int wv = tid >> 6, lane = tid & 63;
    for (int cc = 0; cc < 8; ++cc) {
        int c = wv * 8 + cc, base = c * 16;
        float sa = 0.f, swa = 0.f, ss = 0.f, sws = 0.f;
#pragma unroll
        for (int j = 0; j < 16; ++j) {
            float wn = swn[base + j];
            int row = ssi[base + j];
            float v = Vp[(size_t)row * vstride + lane];
            Vst[(size_t)(base + j) * 64 + lane] = v;
            float w2 = wn * wn, wp = w2 * w2 * wn;
            sa += wn * v; swa += wn;
            ss += wp * v; sws += wp;
        }
        chA[c * 65 + lane] = sa; chS[c * 65 + lane] = ss;
        if (lane == 0) { chA[c * 65 + 64] = swa; chS[c * 65 + 64] = sws; }
    }
    __syncthreads();
    // ---- phase C: 3-phase scans (A: exclusive prefix; S: inclusive suffix) ----
    if (tid < 260) {
        int b = tid / 65, d = tid % 65;
        float run = 0.f;
        for (int c = b * 32; c < b * 32 + 32; ++c) { float v = chA[c * 65 + d]; chA[c * 65 + d] = run; run += v; }
        btA[b][d] = run;
    } else if (tid >= 512 && tid < 772) {
        int u = tid - 512;
        int b = u / 65, d = u % 65;
        float run = 0.f;
        for (int c = b * 32 + 31; c >= b * 32; --c) { run += chS[c * 65 + d]; chS[c * 65 + d] = run; }
        btS[b][d] = run;
    }
    __syncthreads();
    if (tid < 65) {
        float run = 0.f;
        for (int b = 0; b < 4; ++b) { float v = btA[b][tid]; btA[b][tid] = run; run += v; }
        g_chA[(size_t)t * CROWS + 8320 + tid] = run;   // row 128: total
    } else if (tid >= 512 && tid < 577) {
        int d = tid - 512;
        float run = 0.f;
        for (int b = 3; b >= 0; --b) { float v = btS[b][d]; btS[b][d] = run; run += v; }
        g_chS[(size_t)t * CROWS + 8320 + d] = 0.f;     // row 128: empty suffix
    }
    __syncthreads();
    if (tid < 512) {
        for (int i = tid; i < 8320; i += 512) chA[i] += btA[(i / 65) >> 5][i % 65];
    } else {
        for (int i = tid - 512; i < 8320; i += 512) chS[i] += btS[(i / 65) >> 5][i % 65];
    }
    __syncthreads();
    for (int i = tid; i < 8320; i += 1024) {
        g_chA[(size_t)t * CROWS + i] = chA[i];
        g_chS[(size_t)t * CROWS + i] = chS[i];
    }
    // ---- phase D: sort queries by threshold th=-s1 ascending; per-query split k ----
    unsigned long long b0 = pack_key(-s1p[tid], tid);
    unsigned long long b1 = pack_key(-s1p[tid + 1024], tid + 1024);
    bitonic2048(b0, b1, sA, sB, tid);
    float th0 = unpack_key(b0), th1 = unpack_key(b1);
    int lo = 0, hi = NSEG;
    while (lo < hi) { int mid = (lo + hi) >> 1; if (sval[mid] <= th0) lo = mid + 1; else hi = mid; }
    int k0 = lo;
    lo = 0; hi = NSEG;
    while (lo < hi) { int mid = (lo + hi) >> 1; if (sval[mid] <= th1) lo = mid + 1; else hi = mid; }
    int k1 = lo;
    g_th[o + tid] = th0;            g_th[o + tid + 1024] = th1;
    g_qidx[o + tid] = (int)(unsigned)(b0 & 0xffffffffu);
    g_qidx[o + tid + 1024] = (int)(unsigned)(b1 & 0xffffffffu);
    g_kq[o + tid] = k0;             g_kq[o + tid + 1024] = k1;
}

// ---- balanced serve: wave = 32 consecutive sorted queries, constant work per query ----
template <int MODE>  // 0: ELU -> xc ; 1: ELU + log_softmax -> out
__global__ __launch_bounds__(256) void tabquery_k(int heads, int ostride,
                                                  const float* __restrict__ g_wN,
                                                  const float* __restrict__ g_chA,
                                                  const float* __restrict__ g_chS,
                                                  const float* __restrict__ g_M2,
                                                  const float* __restrict__ g_th,
                                                  const int* __restrict__ g_qidx,
                                                  const int* __restrict__ g_kq,
                                                  const float* __restrict__ g_Vs,
                                                  float* __restrict__ out) {
    const int tid = threadIdx.x;
    const int t = blockIdx.y, g = t / heads, h = t % heads;
    const int wv = tid >> 6, lane = tid & 63;
    const int idx0 = blockIdx.x * 128 + wv * 32;
    const float* thp = g_th + (size_t)t * NSEG;
    const int* qip = g_qidx + (size_t)t * NSEG;
    const int* kqp = g_kq + (size_t)t * NSEG;
    const float* cAg = g_chA + (size_t)t * CROWS;
    const float* cSg = g_chS + (size_t)t * CROWS;
    const float* Vst = g_Vs + (size_t)t * NSEG * 64;
    const float* wnp = g_wN + (size_t)t * NSEG;
    const float M2 = g_M2[t];
    float* outp = out + (size_t)g * NSEG * ostride + h * 64;
    // lane-parallel preload of this wave's 32 queries
    int kq_l = 0, qi_l = 0; float th_l = 0.f;
    if (lane < 32) {
        kq_l = kqp[idx0 + lane];
        th_l = thp[idx0 + lane];
        qi_l = qip[idx0 + lane];
    }
    for (int j = 0; j < 32; ++j) {
        int k = __shfl(kq_l, j, 64);
        float thv = __shfl(th_l, j, 64);
        int q = __shfl(qi_l, j, 64);
        int ck = k >> 4; if (ck > 127) ck = 127;
        const float* rA = cAg + ck * 65;
        const float* rS = cSg + (ck + 1) * 65;
        float accA = rA[lane], scaA = rA[64];
        float accS = rS[lane], scaS = rS[64];
        int base = ck * 16;
#pragma unroll
        for (int jj = 0; jj < 16; ++jj) {
            int pos = base + jj;
            float v = Vst[(size_t)pos * 64 + lane];
            float wn = wnp[pos];
            float w2 = wn * wn, wp = w2 * w2 * wn;
            bool isA = pos < k;
            accA += isA ? wn * v : 0.f; scaA += isA ? wn : 0.f;
            accS += isA ? 0.f : wp * v; scaS += isA ? 0.f : wp;
        }
        float s1q = -thv;
        float cc = __expf(-0.8f * fmaxf(s1q + M2, 0.f));
        float o = (accS + cc * accA) / (scaS + cc * scaA);
        o = o > 0.f ? o : expm1f(o);  // ELU
        if (MODE == 0) {
            outp[(size_t)q * ostride + lane] = o;
        } else {
            float m = o;
#pragma unroll
            for (int off = 32; off; off >>= 1) m = fmaxf(m, __shfl_xor(m, off, 64));
            float e = __expf(o - m);
#pragma unroll
            for (int off = 32; off; off >>= 1) e += __shfl_xor(e, off, 64);
            outp[(size_t)q * ostride + lane] = o - m - __logf(e);
        }
    }
}

extern "C" void kernel_launch(void* const* d_in, const int* in_sizes, int n_in,
                              void* d_out, int out_size, void* d_ws, size_t ws_size,
                              hipStream_t stream) {
    const float* h_states = (const float*)d_in[0];
    const float* W_heads = (const float*)d_in[1];
    const float* a_heads = (const float*)d_in[2];
    const float* W_out = (const float*)d_in[3];
    const float* a_out = (const float*)d_in[4];
    float* w = (float*)d_ws;
    float* hh = w + OFF_HH;
    float* xc = w + OFF_XC;
    float* hc = w + OFF_HH;  // reuse: hh dead after layer-1 sortchunkscan (V copied to Vs)
    float* s1h = w + OFF_S1H;
    float* s2h = w + OFF_S2H;
    float* s1o = w + OFF_S1O;
    float* s2o = w + OFF_S2O;
    float* g_wN = w + OFF_WN;
    float* g_th = w + OFF_TH;
    int* g_qidx = (int*)(w + OFF_QIDX);
    int* g_kq = (int*)(w + OFF_KQ);
    float* g_M2 = w + OFF_M2;
    float* g_chA = w + OFF_CHA;
    float* g_chS = w + OFF_CHS;
    float* g_Vs = w + OFF_VS;
    float* outp = (float*)d_out;

    gemm1_k<<<dim3(256, 4), 256, 0, stream>>>(h_states, W_heads, a_heads, hh, s1h, s2h);
    sortchunkscan_k<<<32, 1024, 0, stream>>>(s2h, s1h, hh, 4, 256, g_wN, g_M2, g_th, g_qidx, g_kq,
                                             g_chA, g_chS, g_Vs);
    tabquery_k<0><<<dim3(16, 32), 256, 0, stream>>>(4, 256, g_wN, g_chA, g_chS, g_M2,
                                                    g_th, g_qidx, g_kq, g_Vs, xc);
    gemm2_k<<<256, 256, 0, stream>>>(xc, W_out, a_out, hc, s1o, s2o);
    sortchunkscan_k<<<8, 1024, 0, stream>>>(s2o, s1o, hc, 1, 64, g_wN, g_M2, g_th, g_qidx, g_kq,
                                            g_chA, g_chS, g_Vs);
    tabquery_k<1><<<dim3(16, 8), 256, 0, stream>>>(1, 64, g_wN, g_chA, g_chS, g_M2,
                                                   g_th, g_qidx, g_kq, g_Vs, outp);
}

// Round 8
// 229.720 us; speedup vs baseline: 7.4721x; 1.6358x over previous
//
#include <hip/hip_runtime.h>
#include <math.h>

#define NTOT 16384
#define NSEG 2048
#define CROWS 8385ull   // 129 rows * 65 floats per task (scanned chunk tables + boundary row)

// ws float offsets
#define OFF_HH   0ull         // 16384*256 (hc reuses after layer-1 consumers done)
#define OFF_XC   4194304ull   // 16384*256
#define OFF_S1H  8388608ull   // 65536
#define OFF_S2H  8454144ull   // 65536
#define OFF_S1O  8519680ull   // 16384
#define OFF_S2O  8536064ull   // 16384
#define OFF_WN   8552448ull   // 32*2048
#define OFF_TH   8617984ull   // 32*2048
#define OFF_QIDX 8683520ull   // 32*2048 ints
#define OFF_KQ   8749056ull   // 32*2048 ints
#define OFF_M2   8814592ull   // 32
#define OFF_CHA  8814624ull   // 32*8385
#define OFF_CHS  9082944ull   // 32*8385
#define OFF_VS   9351264ull   // 32*2048*64 -> end 13545568 floats (54.2 MB)

__device__ inline unsigned long long pack_key(float v, int idx) {
    unsigned u = __float_as_uint(v);
    u = (u & 0x80000000u) ? ~u : (u | 0x80000000u);
    return ((unsigned long long)u << 32) | (unsigned)idx;
}
__device__ inline float unpack_key(unsigned long long k) {
    unsigned u = (unsigned)(k >> 32);
    u = (u & 0x80000000u) ? (u ^ 0x80000000u) : ~u;
    return __uint_as_float(u);
}
__device__ inline unsigned long long shfl_xor_u64(unsigned long long x, int mask) {
    unsigned lo = (unsigned)x, hi = (unsigned)(x >> 32);
    lo = (unsigned)__shfl_xor((int)lo, mask, 64);
    hi = (unsigned)__shfl_xor((int)hi, mask, 64);
    return ((unsigned long long)hi << 32) | lo;
}

// verified hybrid register/shuffle/LDS bitonic sort of 2048 u64 (2 elems/thread, 1024 thr)
__device__ inline void bitonic2048(unsigned long long& a0, unsigned long long& a1,
                                   unsigned long long* sA, unsigned long long* sB, int tid) {
    for (int k = 2; k <= 2048; k <<= 1) {
        const bool up0 = (tid & k) == 0;
        const bool up1 = (((tid + 1024) & k) == 0);
        for (int j = k >> 1; j > 0; j >>= 1) {
            if (j >= 1024) {
                unsigned long long lo = a0 < a1 ? a0 : a1;
                unsigned long long hi = a0 < a1 ? a1 : a0;
                a0 = up0 ? lo : hi;
                a1 = up0 ? hi : lo;
            } else if (j >= 64) {
                __syncthreads();
                sA[tid] = a0; sB[tid] = a1;
                __syncthreads();
                unsigned long long p0 = sA[tid ^ j], p1 = sB[tid ^ j];
                bool lower = (tid & j) == 0;
                a0 = ((a0 < p0) == (lower == up0)) ? a0 : p0;
                a1 = ((a1 < p1) == (lower == up1)) ? a1 : p1;
            } else {
                unsigned long long p0 = shfl_xor_u64(a0, j);
                unsigned long long p1 = shfl_xor_u64(a1, j);
                bool lower = (tid & j) == 0;
                a0 = ((a0 < p0) == (lower == up0)) ? a0 : p0;
                a1 = ((a1 < p1) == (lower == up1)) ? a1 : p1;
            }
        }
    }
}

// ---------------- GEMM 1 + fused s1/s2 projection (verified) ----------------
__global__ __launch_bounds__(256) void gemm1_k(const float* __restrict__ X,
                                               const float* __restrict__ Wh,
                                               const float* __restrict__ aH,
                                               float* __restrict__ hh,
                                               float* __restrict__ s1h,
                                               float* __restrict__ s2h) {
    __shared__ float As[64][68];
    __shared__ float Bs[64][68];
    const int tid = threadIdx.x;
    const int bm = blockIdx.x, h = blockIdx.y;
    const int c0 = tid & 63, r0 = tid >> 6;
#pragma unroll
    for (int r = 0; r < 16; ++r) {
        int row = r0 + r * 4;
        As[c0][row] = X[(size_t)(bm * 64 + row) * 64 + c0];
        Bs[row][c0] = Wh[h * 4096 + row * 64 + c0];
    }
    __syncthreads();
    const int tx = tid & 15, ty = tid >> 4;
    const int m0 = ty * 4, n0 = tx * 4;
    float acc[4][4] = {};
#pragma unroll
    for (int kk = 0; kk < 64; ++kk) {
        float4 a = *(const float4*)&As[kk][m0];
        float4 b = *(const float4*)&Bs[kk][n0];
        acc[0][0] += a.x * b.x; acc[0][1] += a.x * b.y; acc[0][2] += a.x * b.z; acc[0][3] += a.x * b.w;
        acc[1][0] += a.y * b.x; acc[1][1] += a.y * b.y; acc[1][2] += a.y * b.z; acc[1][3] += a.y * b.w;
        acc[2][0] += a.z * b.x; acc[2][1] += a.z * b.y; acc[2][2] += a.z * b.z; acc[2][3] += a.z * b.w;
        acc[3][0] += a.w * b.x; acc[3][1] += a.w * b.y; acc[3][2] += a.w * b.z; acc[3][3] += a.w * b.w;
    }
#pragma unroll
    for (int i = 0; i < 4; ++i) {
        float4 v = make_float4(acc[i][0], acc[i][1], acc[i][2], acc[i][3]);
        *(float4*)&hh[(size_t)(bm * 64 + m0 + i) * 256 + h * 64 + n0] = v;
    }
#pragma unroll
    for (int i = 0; i < 4; ++i) {
        float p1 = 0.f, p2 = 0.f;
#pragma unroll
        for (int jj = 0; jj < 4; ++jj) {
            p1 += acc[i][jj] * aH[h * 128 + n0 + jj];
            p2 += acc[i][jj] * aH[h * 128 + 64 + n0 + jj];
        }
#pragma unroll
        for (int off = 8; off; off >>= 1) {
            p1 += __shfl_xor(p1, off, 16);
            p2 += __shfl_xor(p2, off, 16);
        }
        if (tx == 0) {
            s1h[h * NTOT + bm * 64 + m0 + i] = p1;
            s2h[h * NTOT + bm * 64 + m0 + i] = p2;
        }
    }
}

// ---------------- GEMM 2 + fused s1/s2 projection (verified) ----------------
__global__ __launch_bounds__(256) void gemm2_k(const float* __restrict__ XC,
                                               const float* __restrict__ Wo,
                                               const float* __restrict__ aO,
                                               float* __restrict__ hc,
                                               float* __restrict__ s1o,
                                               float* __restrict__ s2o) {
    __shared__ float As[64][68];
    __shared__ float Bs[64][68];
    const int tid = threadIdx.x;
    const int bm = blockIdx.x;
    const int c0 = tid & 63, r0 = tid >> 6;
    const int tx = tid & 15, ty = tid >> 4;
    const int m0 = ty * 4, n0 = tx * 4;
    float acc[4][4] = {};
    for (int kt = 0; kt < 4; ++kt) {
#pragma unroll
        for (int r = 0; r < 16; ++r) {
            int row = r0 + r * 4;
            As[c0][row] = XC[(size_t)(bm * 64 + row) * 256 + kt * 64 + c0];
            Bs[row][c0] = Wo[(kt * 64 + row) * 64 + c0];
        }
        __syncthreads();
#pragma unroll
        for (int kk = 0; kk < 64; ++kk) {
            float4 a = *(const float4*)&As[kk][m0];
            float4 b = *(const float4*)&Bs[kk][n0];
            acc[0][0] += a.x * b.x; acc[0][1] += a.x * b.y; acc[0][2] += a.x * b.z; acc[0][3] += a.x * b.w;
            acc[1][0] += a.y * b.x; acc[1][1] += a.y * b.y; acc[1][2] += a.y * b.z; acc[1][3] += a.y * b.w;
            acc[2][0] += a.z * b.x; acc[2][1] += a.z * b.y; acc[2][2] += a.z * b.z; acc[2][3] += a.z * b.w;
            acc[3][0] += a.w * b.x; acc[3][1] += a.w * b.y; acc[3][2] += a.w * b.z; acc[3][3] += a.w * b.w;
        }
        __syncthreads();
    }
#pragma unroll
    for (int i = 0; i < 4; ++i) {
        float4 v = make_float4(acc[i][0], acc[i][1], acc[i][2], acc[i][3]);
        *(float4*)&hc[(size_t)(bm * 64 + m0 + i) * 64 + n0] = v;
    }
#pragma unroll
    for (int i = 0; i < 4; ++i) {
        float p1 = 0.f, p2 = 0.f;
#pragma unroll
        for (int jj = 0; jj < 4; ++jj) {
            p1 += acc[i][jj] * aO[n0 + jj];
            p2 += acc[i][jj] * aO[64 + n0 + jj];
        }
#pragma unroll
        for (int off = 8; off; off >>= 1) {
            p1 += __shfl_xor(p1, off, 16);
            p2 += __shfl_xor(p2, off, 16);
        }
        if (tx == 0) {
            s1o[bm * 64 + m0 + i] = p1;
            s2o[bm * 64 + m0 + i] = p2;
        }
    }
}

// ---- fused: key sort + V reorder + chunk sums + scans + query sort + per-query k ----
__global__ __launch_bounds__(1024) void sortchunkscan_k(const float* __restrict__ s2_all,
                                                        const float* __restrict__ s1_all,
                                                        const float* __restrict__ V,
                                                        int heads, int vstride,
                                                        float* __restrict__ g_wN,
                                                        float* __restrict__ g_M2,
                                                        float* __restrict__ g_th,
                                                        int* __restrict__ g_qidx,
                                                        int* __restrict__ g_kq,
                                                        float* __restrict__ g_chA, float* __restrict__ g_chS,
                                                        float* __restrict__ g_Vs) {
    __shared__ unsigned long long sA[1024];
    __shared__ unsigned long long sB[1024];
    __shared__ float sval[NSEG];
    __shared__ float swn[NSEG];
    __shared__ int ssi[NSEG];
    __shared__ float chA[8320];
    __shared__ float chS[8320];
    __shared__ float btA[4][65];
    __shared__ float btS[4][65];
    __shared__ float sM2;
    const int tid = threadIdx.x, t = blockIdx.x;
    const int g = t / heads, h = t % heads;
    const float* s2p = s2_all + (size_t)h * NTOT + (size_t)g * NSEG;
    const float* s1p = s1_all + (size_t)h * NTOT + (size_t)g * NSEG;
    const float* Vp = V + (size_t)g * NSEG * vstride + h * 64;
    float* Vst = g_Vs + (size_t)t * NSEG * 64;
    const size_t o = (size_t)t * NSEG;

    // ---- phase A: sort keys ascending ----
    unsigned long long a0 = pack_key(s2p[tid], tid);
    unsigned long long a1 = pack_key(s2p[tid + 1024], tid + 1024);
    bitonic2048(a0, a1, sA, sB, tid);
    float v0 = unpack_key(a0), v1 = unpack_key(a1);
    sval[tid] = v0; sval[tid + 1024] = v1;
    if (tid == 1023) sM2 = v1;
    __syncthreads();
    const float M2 = sM2;
    int i0 = (int)(unsigned)(a0 & 0xffffffffu);
    int i1 = (int)(unsigned)(a1 & 0xffffffffu);
    float w0 = __expf(0.2f * (v0 - M2));
    float w1 = __expf(0.2f * (v1 - M2));
    g_wN[o + tid] = w0; g_wN[o + tid + 1024] = w1;
    swn[tid] = w0; swn[tid + 1024] = w1;
    ssi[tid] = i0; ssi[tid + 1024] = i1;
    if (tid == 0) g_M2[t] = M2;
    __syncthreads();
    // ---- phase B: chunk sums + sorted-V write (wave wv: chunks 8wv..8wv+7; lane = dim) ----
    const int wv = tid >> 6, lane = tid & 63;
    for (int cc = 0; cc < 8; ++cc) {
        int c = wv * 8 + cc, base = c * 16;
        float sa = 0.f, swa = 0.f, ss = 0.f, sws = 0.f;
#pragma unroll
        for (int j = 0; j < 16; ++j) {
            float wn = swn[base + j];
            int row = ssi[base + j];
            float v = Vp[(size_t)row * vstride + lane];
            Vst[(size_t)(base + j) * 64 + lane] = v;
            float w2 = wn * wn, wp = w2 * w2 * wn;
            sa += wn * v; swa += wn;
            ss += wp * v; sws += wp;
        }
        chA[c * 65 + lane] = sa; chS[c * 65 + lane] = ss;
        if (lane == 0) { chA[c * 65 + 64] = swa; chS[c * 65 + 64] = sws; }
    }
    __syncthreads();
    // ---- phase C: 3-phase scans (A: exclusive prefix; S: inclusive suffix) ----
    if (tid < 260) {
        int b = tid / 65, d = tid % 65;
        float run = 0.f;
        for (int c = b * 32; c < b * 32 + 32; ++c) { float v = chA[c * 65 + d]; chA[c * 65 + d] = run; run += v; }
        btA[b][d] = run;
    } else if (tid >= 512 && tid < 772) {
        int u = tid - 512;
        int b = u / 65, d = u % 65;
        float run = 0.f;
        for (int c = b * 32 + 31; c >= b * 32; --c) { run += chS[c * 65 + d]; chS[c * 65 + d] = run; }
        btS[b][d] = run;
    }
    __syncthreads();
    if (tid < 65) {
        float run = 0.f;
        for (int b = 0; b < 4; ++b) { float v = btA[b][tid]; btA[b][tid] = run; run += v; }
        g_chA[(size_t)t * CROWS + 8320 + tid] = run;   // row 128: total
    } else if (tid >= 512 && tid < 577) {
        int d = tid - 512;
        float run = 0.f;
        for (int b = 3; b >= 0; --b) { float v = btS[b][d]; btS[b][d] = run; run += v; }
        g_chS[(size_t)t * CROWS + 8320 + d] = 0.f;     // row 128: empty suffix
    }
    __syncthreads();
    if (tid < 512) {
        for (int i = tid; i < 8320; i += 512) chA[i] += btA[(i / 65) >> 5][i % 65];
    } else {
        for (int i = tid - 512; i < 8320; i += 512) chS[i] += btS[(i / 65) >> 5][i % 65];
    }
    __syncthreads();
    for (int i = tid; i < 8320; i += 1024) {
        g_chA[(size_t)t * CROWS + i] = chA[i];
        g_chS[(size_t)t * CROWS + i] = chS[i];
    }
    // ---- phase D: sort queries by threshold th=-s1 ascending; per-query split k ----
    unsigned long long b0 = pack_key(-s1p[tid], tid);
    unsigned long long b1 = pack_key(-s1p[tid + 1024], tid + 1024);
    bitonic2048(b0, b1, sA, sB, tid);
    float th0 = unpack_key(b0), th1 = unpack_key(b1);
    int lo = 0, hi = NSEG;
    while (lo < hi) { int mid = (lo + hi) >> 1; if (sval[mid] <= th0) lo = mid + 1; else hi = mid; }
    int k0 = lo;
    lo = 0; hi = NSEG;
    while (lo < hi) { int mid = (lo + hi) >> 1; if (sval[mid] <= th1) lo = mid + 1; else hi = mid; }
    int k1 = lo;
    g_th[o + tid] = th0;            g_th[o + tid + 1024] = th1;
    g_qidx[o + tid] = (int)(unsigned)(b0 & 0xffffffffu);
    g_qidx[o + tid + 1024] = (int)(unsigned)(b1 & 0xffffffffu);
    g_kq[o + tid] = k0;             g_kq[o + tid + 1024] = k1;
}

// ---- serve: ONE query per wave; all loads batched up-front; lane = dim ----
template <int MODE>  // 0: ELU -> xc ; 1: ELU + log_softmax -> out
__global__ __launch_bounds__(256) void tabquery_k(int heads, int ostride,
                                                  const float* __restrict__ g_wN,
                                                  const float* __restrict__ g_chA,
                                                  const float* __restrict__ g_chS,
                                                  const float* __restrict__ g_M2,
                                                  const float* __restrict__ g_th,
                                                  const int* __restrict__ g_qidx,
                                                  const int* __restrict__ g_kq,
                                                  const float* __restrict__ g_Vs,
                                                  float* __restrict__ out) {
    const int tid = threadIdx.x;
    const int t = blockIdx.y, g = t / heads, h = t % heads;
    const int wv = tid >> 6, lane = tid & 63;
    const int qslot = blockIdx.x * 4 + wv;  // sorted-query position in this task
    const size_t to = (size_t)t * NSEG;
    const int k = g_kq[to + qslot];
    const float thv = g_th[to + qslot];
    const int q = g_qidx[to + qslot];
    const float M2 = g_M2[t];
    int ck = k >> 4; if (ck > 127) ck = 127;
    const int base = ck * 16;
    const float* rA = g_chA + (size_t)t * CROWS + ck * 65;
    const float* rS = g_chS + (size_t)t * CROWS + (ck + 1) * 65;
    const float* Vst = g_Vs + (size_t)t * NSEG * 64 + (size_t)base * 64;
    // batch ALL loads: 2 row entries + 2 scale entries + 16 wn (lanes 0-15) + 16 V rows
    float accA = rA[lane], scaA = rA[64];
    float accS = rS[lane], scaS = rS[64];
    float wnl = (lane < 16) ? g_wN[to + base + lane] : 0.f;
    float vv[16];
#pragma unroll
    for (int j = 0; j < 16; ++j) vv[j] = Vst[(size_t)j * 64 + lane];
#pragma unroll
    for (int j = 0; j < 16; ++j) {
        float wn = __shfl(wnl, j, 64);
        float w2 = wn * wn, wp = w2 * w2 * wn;
        bool isA = (base + j) < k;
        accA += isA ? wn * vv[j] : 0.f; scaA += isA ? wn : 0.f;
        accS += isA ? 0.f : wp * vv[j]; scaS += isA ? 0.f : wp;
    }
    float s1q = -thv;
    float cc = __expf(-0.8f * fmaxf(s1q + M2, 0.f));
    float o = (accS + cc * accA) / (scaS + cc * scaA);
    o = o > 0.f ? o : expm1f(o);  // ELU
    float* outp = out + (size_t)g * NSEG * ostride + h * 64;
    if (MODE == 0) {
        outp[(size_t)q * ostride + lane] = o;
    } else {
        float m = o;
#pragma unroll
        for (int off = 32; off; off >>= 1) m = fmaxf(m, __shfl_xor(m, off, 64));
        float e = __expf(o - m);
#pragma unroll
        for (int off = 32; off; off >>= 1) e += __shfl_xor(e, off, 64);
        outp[(size_t)q * ostride + lane] = o - m - __logf(e);
    }
}

extern "C" void kernel_launch(void* const* d_in, const int* in_sizes, int n_in,
                              void* d_out, int out_size, void* d_ws, size_t ws_size,
                              hipStream_t stream) {
    const float* h_states = (const float*)d_in[0];
    const float* W_heads = (const float*)d_in[1];
    const float* a_heads = (const float*)d_in[2];
    const float* W_out = (const float*)d_in[3];
    const float* a_out = (const float*)d_in[4];
    float* w = (float*)d_ws;
    float* hh = w + OFF_HH;
    float* xc = w + OFF_XC;
    float* hc = w + OFF_HH;  // reuse: hh dead after layer-1 sortchunkscan (V copied to Vs)
    float* s1h = w + OFF_S1H;
    float* s2h = w + OFF_S2H;
    float* s1o = w + OFF_S1O;
    float* s2o = w + OFF_S2O;
    float* g_wN = w + OFF_WN;
    float* g_th = w + OFF_TH;
    int* g_qidx = (int*)(w + OFF_QIDX);
    int* g_kq = (int*)(w + OFF_KQ);
    float* g_M2 = w + OFF_M2;
    float* g_chA = w + OFF_CHA;
    float* g_chS = w + OFF_CHS;
    float* g_Vs = w + OFF_VS;
    float* outp = (float*)d_out;

    gemm1_k<<<dim3(256, 4), 256, 0, stream>>>(h_states, W_heads, a_heads, hh, s1h, s2h);
    sortchunkscan_k<<<32, 1024, 0, stream>>>(s2h, s1h, hh, 4, 256, g_wN, g_M2, g_th, g_qidx, g_kq,
                                             g_chA, g_chS, g_Vs);
    tabquery_k<0><<<dim3(512, 32), 256, 0, stream>>>(4, 256, g_wN, g_chA, g_chS, g_M2,
                                                     g_th, g_qidx, g_kq, g_Vs, xc);
    gemm2_k<<<256, 256, 0, stream>>>(xc, W_out, a_out, hc, s1o, s2o);
    sortchunkscan_k<<<8, 1024, 0, stream>>>(s2o, s1o, hc, 1, 64, g_wN, g_M2, g_th, g_qidx, g_kq,
                                            g_chA, g_chS, g_Vs);
    tabquery_k<1><<<dim3(512, 8), 256, 0, stream>>>(1, 64, g_wN, g_chA, g_chS, g_M2,
                                                    g_th, g_qidx, g_kq, g_Vs, outp);
}